// Round 13
// baseline (144.375 us; speedup 1.0000x reference)
//
#include <hip/hip_runtime.h>
#include <math.h>

typedef float  f32x4   __attribute__((ext_vector_type(4)));
typedef float  f32x16  __attribute__((ext_vector_type(16)));
typedef __bf16 bf16x8  __attribute__((ext_vector_type(8)));
typedef __bf16 bf16x4  __attribute__((ext_vector_type(4)));

#define MFMA16(a, b, c) __builtin_amdgcn_mfma_f32_16x16x32_bf16((a), (b), (c), 0, 0, 0)
#define MFMA32(a, b, c) __builtin_amdgcn_mfma_f32_32x32x16_bf16((a), (b), (c), 0, 0, 0)

typedef __attribute__((address_space(3))) unsigned int lds_u32;
typedef __attribute__((address_space(1))) const unsigned int glb_u32;

__device__ __forceinline__ void gload16(const __bf16* g, char* l) {
    __builtin_amdgcn_global_load_lds((glb_u32*)g, (lds_u32*)l, 16, 0, 0);
}

// problem sizes
static constexpr int BATCH = 4;
static constexpr int CH    = 256;
static constexpr int M_TOT = BATCH * 4096;  // 16384

// qkv softmax pre-scale folded into Q: 0.125 * log2(e)
static constexpr float QSCALE = 0.18033688011112042f;

// workspace layout (bytes, 16-aligned)
static constexpr size_t OFF_WQKV  = 0;                              // 196608 bf16
static constexpr size_t OFF_WOUT  = 196608ull * 2;                  // 65536 bf16
static constexpr size_t OFF_STATS = OFF_WOUT + 65536ull * 2;        // 128 float2
static constexpr size_t OFF_HID   = OFF_STATS + 1024;               // hid / attn_out bf16
static constexpr size_t OFF_Q     = OFF_HID + (size_t)M_TOT * CH * 2;
static constexpr size_t OFF_K     = OFF_Q   + (size_t)M_TOT * CH * 2;
static constexpr size_t OFF_V     = OFF_K   + (size_t)M_TOT * CH * 2;  // V^T [16][64][4096]

// ---------------------------------------------------------------------------
// 1) fused: GN stats (blocks 0..127) + weight convert/permute (blocks 128..1151)
// ---------------------------------------------------------------------------
__global__ __launch_bounds__(256) void pre_kernel(const float* __restrict__ x,
                                                  float2* __restrict__ stats,
                                                  const float* __restrict__ wq,
                                                  const float* __restrict__ wo,
                                                  __bf16* __restrict__ wqf,
                                                  __bf16* __restrict__ wof) {
    if (blockIdx.x < 128) {
        int bg = blockIdx.x;  // 0..127
        const float4* p = (const float4*)(x + (size_t)bg * 32768);
        float s = 0.f, ss = 0.f;
        for (int i = threadIdx.x; i < 8192; i += 256) {
            float4 v = p[i];
            s  += (v.x + v.y) + (v.z + v.w);
            ss += v.x * v.x + v.y * v.y + v.z * v.z + v.w * v.w;
        }
#pragma unroll
        for (int d = 32; d > 0; d >>= 1) { s += __shfl_down(s, d); ss += __shfl_down(ss, d); }
        __shared__ float sh[8];
        int w = threadIdx.x >> 6, l = threadIdx.x & 63;
        if (l == 0) { sh[w] = s; sh[4 + w] = ss; }
        __syncthreads();
        if (threadIdx.x == 0) {
            float S = sh[0] + sh[1] + sh[2] + sh[3];
            float SS = sh[4] + sh[5] + sh[6] + sh[7];
            float mean = S * (1.f / 32768.f);
            float var  = SS * (1.f / 32768.f) - mean * mean;
            stats[bg] = make_float2(mean, rsqrtf(var + 1e-5f));
        }
    } else {
        int i = (blockIdx.x - 128) * 256 + threadIdx.x;   // 0 .. 262143
        if (i < 196608) {
            int e = i & 7, l = (i >> 3) & 63, kk = (i >> 9) & 7, jt = i >> 12;  // jt 0..47
            int kidx = kk * 32 + ((l >> 4) << 3) + e;
            int n = jt * 16 + (l & 15);
            wqf[i] = (__bf16)wq[kidx * 768 + n];
        } else {
            int i2 = i - 196608;                  // 0 .. 65535
            int e = i2 & 7, l = (i2 >> 3) & 63, kk = (i2 >> 9) & 7, jt = i2 >> 12;  // jt 0..15
            int kidx = kk * 32 + ((l >> 4) << 3) + e;
            int n = jt * 16 + (l & 15);
            wof[i2] = (__bf16)wo[kidx * 256 + n];
        }
    }
}

// ---------------------------------------------------------------------------
// 2) GN apply + transpose: hid[b][n][c] = gn(x)[b][c][n]  (bf16)
// ---------------------------------------------------------------------------
__global__ __launch_bounds__(256) void gn_apply(const float* __restrict__ x,
                                                const float* __restrict__ gamma,
                                                const float* __restrict__ beta,
                                                const float2* __restrict__ stats,
                                                __bf16* __restrict__ hid) {
    int b  = blockIdx.x >> 6;
    int n0 = (blockIdx.x & 63) << 6;
    int c  = threadIdx.x;
    float2 st = stats[b * 32 + (c >> 3)];
    float gm = gamma[c] * st.y;
    float bt = beta[c] - st.x * gm;
    const float* xp = x + ((size_t)(b * 256 + c)) * 4096 + n0;
    __bf16* hp = hid + ((size_t)(b * 4096 + n0)) * 256 + c;
#pragma unroll
    for (int j4 = 0; j4 < 16; ++j4) {
        float4 v = *(const float4*)(xp + j4 * 4);
        hp[(size_t)(j4 * 4 + 0) * 256] = (__bf16)(v.x * gm + bt);
        hp[(size_t)(j4 * 4 + 1) * 256] = (__bf16)(v.y * gm + bt);
        hp[(size_t)(j4 * 4 + 2) * 256] = (__bf16)(v.z * gm + bt);
        hp[(size_t)(j4 * 4 + 3) * 256] = (__bf16)(v.w * gm + bt);
    }
}

// ---------------------------------------------------------------------------
// 3) QKV GEMM: [16384,256] x [256,768] + bias.
//    q,k -> [B,H,4096,64];  v -> V^T [B*H, 64, 4096] with kappa column order
//    (within each 16-col block, position c holds token 8*((c>>2)&1)+4*(c>>3)+(c&3))
//    via LDS-transpose epilogue. Q pre-scaled by 0.125*log2(e).
// ---------------------------------------------------------------------------
__global__ __launch_bounds__(256) void qkv_gemm(const __bf16* __restrict__ hid,
                                                const __bf16* __restrict__ wf,
                                                const float* __restrict__ bqkv,
                                                __bf16* __restrict__ qb,
                                                __bf16* __restrict__ kb,
                                                __bf16* __restrict__ vb) {
    const int mt = blockIdx.x, nt = blockIdx.y;
    const int tid = threadIdx.x;
    const int w = tid >> 6, l = tid & 63;
    const int lr = l & 15, lh = l >> 4;
    f32x4 acc[4] = {{0.f,0.f,0.f,0.f},{0.f,0.f,0.f,0.f},{0.f,0.f,0.f,0.f},{0.f,0.f,0.f,0.f}};
    const __bf16* ap = hid + (size_t)(mt * 64 + w * 16 + lr) * 256 + lh * 8;
#pragma unroll
    for (int kk = 0; kk < 8; ++kk) {
        bf16x8 a = *(const bf16x8*)(ap + kk * 32);
#pragma unroll
        for (int fj = 0; fj < 4; ++fj) {
            bf16x8 bf = *(const bf16x8*)(wf + (size_t)(((nt * 4 + fj) * 8 + kk) * 64 + l) * 8);
            acc[fj] = MFMA16(a, bf, acc[fj]);
        }
    }
    const int part = nt % 3;           // 0=q 1=k 2=v (uniform per block)
    const int head = nt / 3;
    const int b  = mt >> 6;
    const int n0 = (mt & 63) * 64;

    if (part == 2) {
        // V block: route through LDS transpose, store V^T with kappa col order
        __shared__ float tile[64][72];
#pragma unroll
        for (int fj = 0; fj < 4; ++fj) {
            float bias = bqkv[head * 192 + 128 + fj * 16 + lr];
#pragma unroll
            for (int r = 0; r < 4; ++r)
                tile[w * 16 + lh * 4 + r][fj * 16 + lr] = acc[fj][r] + bias;
        }
        __syncthreads();
        int dd = tid >> 2, nq = tid & 3;
        __bf16* dstrow = vb + ((size_t)((b * 4 + head) * 64 + dd)) * 4096 + n0 + nq * 16;
        bf16x8 w0, w1;
#pragma unroll
        for (int cc = 0; cc < 8; ++cc) {
            int nl0 = nq * 16 + 8 * ((cc >> 2) & 1) + 4 * (cc >> 3) + (cc & 3);
            int cc1 = cc + 8;
            int nl1 = nq * 16 + 8 * ((cc1 >> 2) & 1) + 4 * (cc1 >> 3) + (cc1 & 3);
            w0[cc] = (__bf16)tile[nl0][dd];
            w1[cc] = (__bf16)tile[nl1][dd];
        }
        *(bf16x8*)dstrow = w0;
        *(bf16x8*)(dstrow + 8) = w1;
    } else {
        __bf16* dst = (part == 0) ? qb : kb;
        const float sc = (part == 0) ? QSCALE : 1.0f;
        int mbase = w * 16 + lh * 4;
#pragma unroll
        for (int fj = 0; fj < 4; ++fj) {
            int dd = fj * 16 + lr;
            float bias = bqkv[head * 192 + part * 64 + dd];
#pragma unroll
            for (int r = 0; r < 4; ++r) {
                int n = n0 + mbase + r;
                dst[((size_t)((b * 4 + head) * 4096 + n)) * 64 + dd] = (__bf16)((acc[fj][r] + bias) * sc);
            }
        }
    }
}

// ---------------------------------------------------------------------------
// 4) Flash attention, swapped-operand, STATIC softmax, 32x32x16 MFMAs,
//    V^T-in-global (kappa-ordered): PV A-frags are plain b128 LDS reads at the
//    SAME offsets as K frags; P B-frags = raw exp2'd S registers (identity).
//    Grid 512 (XCD swizzle), 4 waves x 32 q-rows (128-row supertile).
//    No tr-reads, no inline-asm waits — compiler schedules lgkmcnt.
// ---------------------------------------------------------------------------
__global__ __launch_bounds__(256, 2) void attn_fwd(const __bf16* __restrict__ q,
                                                   const __bf16* __restrict__ k,
                                                   const __bf16* __restrict__ vt,
                                                   __bf16* __restrict__ ao) {
    const int id = blockIdx.x;
    const int within = id >> 3;                       // 0..63
    const int bh = ((id & 7) << 1) + (within >> 5);   // XCD (id&7) owns bh pair
    const int q0 = (within & 31) * 128;
    const int tid = threadIdx.x;
    const int wv = tid >> 6, l = tid & 63;
    const int l31 = l & 31, h = l >> 5;

    __shared__ __attribute__((aligned(16))) char smem[32768];  // K dbuf 16K | V^T dbuf 16K

    const size_t base = (size_t)bh * (4096 * 64);

    // ---- staging addresses (chunk c = wv*64 + l, and +256) ----
    const int c0 = wv * 64 + l;
    const int rK = c0 >> 3, cbK = l & 7;
    const int gk0 = rK * 64 + (cbK ^ (rK & 7)) * 8;            // K: row=key (stride 64)
    const int gk1 = gk0 + 2048;                                 // +32 rows
    const int gv0 = rK * 4096 + (cbK ^ (rK & 7)) * 8;           // V^T: row=d (stride 4096)
    const int gv1 = gv0 + 32 * 4096;                            // +32 d-rows
    const int lw0 = wv * 1024;                                  // wave-uniform LDS bases
    const int lw1 = 4096 + wv * 1024;

    const __bf16* kg = k + base;
    const __bf16* vg = vt + base;   // V^T [64][4096]

    // fragment byte offsets (shared by K and V^T): row = b32*32 + l31
    int foff[2][4];
#pragma unroll
    for (int b32 = 0; b32 < 2; ++b32) {
        int row = b32 * 32 + l31;
#pragma unroll
        for (int s = 0; s < 4; ++s)
            foff[b32][s] = row * 128 + ((s * 32 + h * 16) ^ ((row & 7) << 4));
    }

    // Q B-frags: lane holds Q[q = q0+wv*32+l31][ks*16 + h*8 + e]
    bf16x8 qf[4];
    {
        const __bf16* qp = q + base + (size_t)(q0 + wv * 32 + l31) * 64 + h * 8;
#pragma unroll
        for (int ks = 0; ks < 4; ++ks) qf[ks] = *(const bf16x8*)(qp + ks * 16);
    }
    bf16x8 ones;
#pragma unroll
    for (int e = 0; e < 8; ++e) ones[e] = (__bf16)1.0f;

    f32x16 O0 = (f32x16)0.0f, O1 = (f32x16)0.0f, LS = (f32x16)0.0f;

    // prologue: stage tile 0 into buf 0
    gload16(kg + gk0, smem + lw0);
    gload16(kg + gk1, smem + lw1);
    gload16(vg + gv0, smem + 16384 + lw0);
    gload16(vg + gv1, smem + 16384 + lw1);
    __syncthreads();

    auto body = [&](const char* Kc, const char* Vc, char* kd, char* vd, int tnext) {
        // issue next-tile staging into the other buffer
        if (tnext < 64) {
            const __bf16* kp = kg + (size_t)tnext * 4096;
            const __bf16* vp = vg + (size_t)tnext * 64;
            gload16(kp + gk0, kd + lw0);
            gload16(kp + gk1, kd + lw1);
            gload16(vp + gv0, vd + lw0);
            gload16(vp + gv1, vd + lw1);
        }

        // ---- S^T = K Q^T (2 x 4 chained MFMA32) ----
        f32x16 S0 = (f32x16)0.0f, S1 = (f32x16)0.0f;
        __builtin_amdgcn_s_setprio(1);
#pragma unroll
        for (int ks = 0; ks < 4; ++ks) {
            bf16x8 ka0 = *(const bf16x8*)(Kc + foff[0][ks]);
            bf16x8 ka1 = *(const bf16x8*)(Kc + foff[1][ks]);
            S0 = MFMA32(ka0, qf[ks], S0);
            S1 = MFMA32(ka1, qf[ks], S1);
        }
        __builtin_amdgcn_s_setprio(0);

        // ---- static softmax: B_s[e] = bf16(exp2(S regs)) — identity map ----
        bf16x8 B0, B1, B2, B3;
#pragma unroll
        for (int e = 0; e < 8; ++e) {
            B0[e] = (__bf16)__builtin_amdgcn_exp2f(S0[e]);
            B1[e] = (__bf16)__builtin_amdgcn_exp2f(S0[8 + e]);
            B2[e] = (__bf16)__builtin_amdgcn_exp2f(S1[e]);
            B3[e] = (__bf16)__builtin_amdgcn_exp2f(S1[8 + e]);
        }

        // ---- O^T += V^T P ; lsum via ones-MFMA (A-frags: plain b128 reads) ----
        __builtin_amdgcn_s_setprio(1);
        {
            bf16x8 v00 = *(const bf16x8*)(Vc + foff[0][0]);
            bf16x8 v10 = *(const bf16x8*)(Vc + foff[1][0]);
            O0 = MFMA32(v00, B0, O0);
            O1 = MFMA32(v10, B0, O1);
            LS = MFMA32(ones, B0, LS);
            bf16x8 v01 = *(const bf16x8*)(Vc + foff[0][1]);
            bf16x8 v11 = *(const bf16x8*)(Vc + foff[1][1]);
            O0 = MFMA32(v01, B1, O0);
            O1 = MFMA32(v11, B1, O1);
            LS = MFMA32(ones, B1, LS);
            bf16x8 v02 = *(const bf16x8*)(Vc + foff[0][2]);
            bf16x8 v12 = *(const bf16x8*)(Vc + foff[1][2]);
            O0 = MFMA32(v02, B2, O0);
            O1 = MFMA32(v12, B2, O1);
            LS = MFMA32(ones, B2, LS);
            bf16x8 v03 = *(const bf16x8*)(Vc + foff[0][3]);
            bf16x8 v13 = *(const bf16x8*)(Vc + foff[1][3]);
            O0 = MFMA32(v03, B3, O0);
            O1 = MFMA32(v13, B3, O1);
            LS = MFMA32(ones, B3, LS);
        }
        __builtin_amdgcn_s_setprio(0);

        __syncthreads();   // implicit vmcnt(0): staging landed; buf flip safe
    };

    for (int t = 0; t < 64; t += 2) {
        body(smem,        smem + 16384,        smem + 8192, smem + 16384 + 8192, t + 1);
        body(smem + 8192, smem + 16384 + 8192, smem,        smem + 16384,        t + 2);
    }

    // epilogue: every lane holds the full denominator in LS (any reg)
    float inv = 1.0f / LS[0];
    int b = bh >> 2, hd = bh & 3;
    int n = q0 + wv * 32 + l31;
    __bf16* dst = ao + ((size_t)(b * 4096 + n)) * 256 + hd * 64 + h * 4;
#pragma unroll
    for (int dt = 0; dt < 2; ++dt) {
        const f32x16& O = dt ? O1 : O0;
#pragma unroll
        for (int g = 0; g < 4; ++g) {
            bf16x4 pk;
#pragma unroll
            for (int m = 0; m < 4; ++m) pk[m] = (__bf16)(O[g * 4 + m] * inv);
            *(bf16x4*)(dst + dt * 32 + g * 8) = pk;
        }
    }
}

// ---------------------------------------------------------------------------
// 5) out projection + bias + residual + 1/sqrt(2), transposed store [B,C,N]
// ---------------------------------------------------------------------------
__global__ __launch_bounds__(256) void out_gemm(const __bf16* __restrict__ ao,
                                                const __bf16* __restrict__ wf,
                                                const float* __restrict__ bout,
                                                const float* __restrict__ x,
                                                float* __restrict__ out) {
    const int mt = blockIdx.x, nt = blockIdx.y;
    const int tid = threadIdx.x;
    const int w = tid >> 6, l = tid & 63;
    const int lr = l & 15, lh = l >> 4;
    f32x4 acc[4] = {{0.f,0.f,0.f,0.f},{0.f,0.f,0.f,0.f},{0.f,0.f,0.f,0.f},{0.f,0.f,0.f,0.f}};
    const __bf16* ap = ao + (size_t)(mt * 64 + w * 16 + lr) * 256 + lh * 8;
#pragma unroll
    for (int kk = 0; kk < 8; ++kk) {
        bf16x8 a = *(const bf16x8*)(ap + kk * 32);
#pragma unroll
        for (int fj = 0; fj < 4; ++fj) {
            bf16x8 bf = *(const bf16x8*)(wf + (size_t)(((nt * 4 + fj) * 8 + kk) * 64 + l) * 8);
            acc[fj] = MFMA16(a, bf, acc[fj]);
        }
    }
    __shared__ float tile[64][72];
#pragma unroll
    for (int fj = 0; fj < 4; ++fj) {
        float bias = bout[nt * 64 + fj * 16 + lr];
#pragma unroll
        for (int r = 0; r < 4; ++r)
            tile[w * 16 + lh * 4 + r][fj * 16 + lr] = acc[fj][r] + bias;
    }
    __syncthreads();
    int b  = mt >> 6;
    int n0 = (mt & 63) * 64;
    int c0 = nt * 64;
    int cl = tid >> 2, nq = tid & 3;
    size_t gbase = ((size_t)(b * 256 + c0 + cl)) * 4096 + n0 + nq * 16;
#pragma unroll
    for (int i = 0; i < 16; i += 4) {
        float4 xv = *(const float4*)(x + gbase + i);
        float4 ov;
        ov.x = (tile[nq * 16 + i + 0][cl] + xv.x) * 0.70710678118654752f;
        ov.y = (tile[nq * 16 + i + 1][cl] + xv.y) * 0.70710678118654752f;
        ov.z = (tile[nq * 16 + i + 2][cl] + xv.z) * 0.70710678118654752f;
        ov.w = (tile[nq * 16 + i + 3][cl] + xv.w) * 0.70710678118654752f;
        *(float4*)(out + gbase + i) = ov;
    }
}

// ---------------------------------------------------------------------------
extern "C" void kernel_launch(void* const* d_in, const int* in_sizes, int n_in,
                              void* d_out, int out_size, void* d_ws, size_t ws_size,
                              hipStream_t stream) {
    const float* x     = (const float*)d_in[0];
    const float* gamma = (const float*)d_in[1];
    const float* beta  = (const float*)d_in[2];
    const float* W_qkv = (const float*)d_in[3];
    const float* b_qkv = (const float*)d_in[4];
    const float* W_out = (const float*)d_in[5];
    const float* b_out = (const float*)d_in[6];
    float* out = (float*)d_out;
    char* ws = (char*)d_ws;

    __bf16* wqf   = (__bf16*)(ws + OFF_WQKV);
    __bf16* wof   = (__bf16*)(ws + OFF_WOUT);
    float2* stats = (float2*)(ws + OFF_STATS);
    __bf16* hid   = (__bf16*)(ws + OFF_HID);   // hid, then attn_out
    __bf16* qb    = (__bf16*)(ws + OFF_Q);
    __bf16* kb    = (__bf16*)(ws + OFF_K);
    __bf16* vbt   = (__bf16*)(ws + OFF_V);     // V^T kappa-ordered

    pre_kernel<<<1152, 256, 0, stream>>>(x, stats, W_qkv, W_out, wqf, wof);
    gn_apply<<<256, 256, 0, stream>>>(x, gamma, beta, stats, hid);
    qkv_gemm<<<dim3(256, 12), 256, 0, stream>>>(hid, wqf, b_qkv, qb, kb, vbt);
    attn_fwd<<<512, 256, 0, stream>>>(qb, kb, vbt, hid);
    out_gemm<<<dim3(256, 4), 256, 0, stream>>>(hid, wof, b_out, x, out);
}

// Round 14
// 142.413 us; speedup vs baseline: 1.0138x; 1.0138x over previous
//
#include <hip/hip_runtime.h>
#include <math.h>

typedef float  f32x4   __attribute__((ext_vector_type(4)));
typedef float  f32x16  __attribute__((ext_vector_type(16)));
typedef __bf16 bf16x8  __attribute__((ext_vector_type(8)));
typedef __bf16 bf16x4  __attribute__((ext_vector_type(4)));

#define MFMA16(a, b, c) __builtin_amdgcn_mfma_f32_16x16x32_bf16((a), (b), (c), 0, 0, 0)
#define MFMA32(a, b, c) __builtin_amdgcn_mfma_f32_32x32x16_bf16((a), (b), (c), 0, 0, 0)

typedef __attribute__((address_space(3))) unsigned int lds_u32;
typedef __attribute__((address_space(1))) const unsigned int glb_u32;

__device__ __forceinline__ void gload16(const __bf16* g, char* l) {
    __builtin_amdgcn_global_load_lds((glb_u32*)g, (lds_u32*)l, 16, 0, 0);
}

// problem sizes
static constexpr int BATCH = 4;
static constexpr int CH    = 256;
static constexpr int M_TOT = BATCH * 4096;  // 16384

// qkv softmax pre-scale folded into Q: 0.125 * log2(e)
static constexpr float QSCALE = 0.18033688011112042f;

// workspace layout (bytes, 16-aligned)
static constexpr size_t OFF_WQKV  = 0;                              // 196608 bf16
static constexpr size_t OFF_WOUT  = 196608ull * 2;                  // 65536 bf16
static constexpr size_t OFF_STATS = OFF_WOUT + 65536ull * 2;        // 128 float2
static constexpr size_t OFF_HID   = OFF_STATS + 1024;               // hid / attn_out bf16
static constexpr size_t OFF_Q     = OFF_HID + (size_t)M_TOT * CH * 2;
static constexpr size_t OFF_K     = OFF_Q   + (size_t)M_TOT * CH * 2;
static constexpr size_t OFF_V     = OFF_K   + (size_t)M_TOT * CH * 2;  // V^T [16][64][4096]

// ---------------------------------------------------------------------------
// 1) fused: GN stats (blocks 0..127) + weight convert/permute (blocks 128..1151)
// ---------------------------------------------------------------------------
__global__ __launch_bounds__(256) void pre_kernel(const float* __restrict__ x,
                                                  float2* __restrict__ stats,
                                                  const float* __restrict__ wq,
                                                  const float* __restrict__ wo,
                                                  __bf16* __restrict__ wqf,
                                                  __bf16* __restrict__ wof) {
    if (blockIdx.x < 128) {
        int bg = blockIdx.x;  // 0..127
        const float4* p = (const float4*)(x + (size_t)bg * 32768);
        float s = 0.f, ss = 0.f;
        for (int i = threadIdx.x; i < 8192; i += 256) {
            float4 v = p[i];
            s  += (v.x + v.y) + (v.z + v.w);
            ss += v.x * v.x + v.y * v.y + v.z * v.z + v.w * v.w;
        }
#pragma unroll
        for (int d = 32; d > 0; d >>= 1) { s += __shfl_down(s, d); ss += __shfl_down(ss, d); }
        __shared__ float sh[8];
        int w = threadIdx.x >> 6, l = threadIdx.x & 63;
        if (l == 0) { sh[w] = s; sh[4 + w] = ss; }
        __syncthreads();
        if (threadIdx.x == 0) {
            float S = sh[0] + sh[1] + sh[2] + sh[3];
            float SS = sh[4] + sh[5] + sh[6] + sh[7];
            float mean = S * (1.f / 32768.f);
            float var  = SS * (1.f / 32768.f) - mean * mean;
            stats[bg] = make_float2(mean, rsqrtf(var + 1e-5f));
        }
    } else {
        int i = (blockIdx.x - 128) * 256 + threadIdx.x;   // 0 .. 262143
        if (i < 196608) {
            int e = i & 7, l = (i >> 3) & 63, kk = (i >> 9) & 7, jt = i >> 12;  // jt 0..47
            int kidx = kk * 32 + ((l >> 4) << 3) + e;
            int n = jt * 16 + (l & 15);
            wqf[i] = (__bf16)wq[kidx * 768 + n];
        } else {
            int i2 = i - 196608;                  // 0 .. 65535
            int e = i2 & 7, l = (i2 >> 3) & 63, kk = (i2 >> 9) & 7, jt = i2 >> 12;  // jt 0..15
            int kidx = kk * 32 + ((l >> 4) << 3) + e;
            int n = jt * 16 + (l & 15);
            wof[i2] = (__bf16)wo[kidx * 256 + n];
        }
    }
}

// ---------------------------------------------------------------------------
// 2) GN apply + transpose: hid[b][n][c] = gn(x)[b][c][n]  (bf16)
// ---------------------------------------------------------------------------
__global__ __launch_bounds__(256) void gn_apply(const float* __restrict__ x,
                                                const float* __restrict__ gamma,
                                                const float* __restrict__ beta,
                                                const float2* __restrict__ stats,
                                                __bf16* __restrict__ hid) {
    int b  = blockIdx.x >> 6;
    int n0 = (blockIdx.x & 63) << 6;
    int c  = threadIdx.x;
    float2 st = stats[b * 32 + (c >> 3)];
    float gm = gamma[c] * st.y;
    float bt = beta[c] - st.x * gm;
    const float* xp = x + ((size_t)(b * 256 + c)) * 4096 + n0;
    __bf16* hp = hid + ((size_t)(b * 4096 + n0)) * 256 + c;
#pragma unroll
    for (int j4 = 0; j4 < 16; ++j4) {
        float4 v = *(const float4*)(xp + j4 * 4);
        hp[(size_t)(j4 * 4 + 0) * 256] = (__bf16)(v.x * gm + bt);
        hp[(size_t)(j4 * 4 + 1) * 256] = (__bf16)(v.y * gm + bt);
        hp[(size_t)(j4 * 4 + 2) * 256] = (__bf16)(v.z * gm + bt);
        hp[(size_t)(j4 * 4 + 3) * 256] = (__bf16)(v.w * gm + bt);
    }
}

// ---------------------------------------------------------------------------
// 3) QKV GEMM: [16384,256] x [256,768] + bias.
//    q,k -> [B,H,4096,64];  v -> V^T [B*H, 64, 4096] with kappa column order
//    (within each 16-col block, position c holds token 8*((c>>2)&1)+4*(c>>3)+(c&3))
//    via LDS-transpose epilogue. Q pre-scaled by 0.125*log2(e).
// ---------------------------------------------------------------------------
__global__ __launch_bounds__(256) void qkv_gemm(const __bf16* __restrict__ hid,
                                                const __bf16* __restrict__ wf,
                                                const float* __restrict__ bqkv,
                                                __bf16* __restrict__ qb,
                                                __bf16* __restrict__ kb,
                                                __bf16* __restrict__ vb) {
    const int mt = blockIdx.x, nt = blockIdx.y;
    const int tid = threadIdx.x;
    const int w = tid >> 6, l = tid & 63;
    const int lr = l & 15, lh = l >> 4;
    f32x4 acc[4] = {{0.f,0.f,0.f,0.f},{0.f,0.f,0.f,0.f},{0.f,0.f,0.f,0.f},{0.f,0.f,0.f,0.f}};
    const __bf16* ap = hid + (size_t)(mt * 64 + w * 16 + lr) * 256 + lh * 8;
#pragma unroll
    for (int kk = 0; kk < 8; ++kk) {
        bf16x8 a = *(const bf16x8*)(ap + kk * 32);
#pragma unroll
        for (int fj = 0; fj < 4; ++fj) {
            bf16x8 bf = *(const bf16x8*)(wf + (size_t)(((nt * 4 + fj) * 8 + kk) * 64 + l) * 8);
            acc[fj] = MFMA16(a, bf, acc[fj]);
        }
    }
    const int part = nt % 3;           // 0=q 1=k 2=v (uniform per block)
    const int head = nt / 3;
    const int b  = mt >> 6;
    const int n0 = (mt & 63) * 64;

    if (part == 2) {
        // V block: route through LDS transpose, store V^T with kappa col order
        __shared__ float tile[64][72];
#pragma unroll
        for (int fj = 0; fj < 4; ++fj) {
            float bias = bqkv[head * 192 + 128 + fj * 16 + lr];
#pragma unroll
            for (int r = 0; r < 4; ++r)
                tile[w * 16 + lh * 4 + r][fj * 16 + lr] = acc[fj][r] + bias;
        }
        __syncthreads();
        int dd = tid >> 2, nq = tid & 3;
        __bf16* dstrow = vb + ((size_t)((b * 4 + head) * 64 + dd)) * 4096 + n0 + nq * 16;
        bf16x8 w0, w1;
#pragma unroll
        for (int cc = 0; cc < 8; ++cc) {
            int nl0 = nq * 16 + 8 * ((cc >> 2) & 1) + 4 * (cc >> 3) + (cc & 3);
            int cc1 = cc + 8;
            int nl1 = nq * 16 + 8 * ((cc1 >> 2) & 1) + 4 * (cc1 >> 3) + (cc1 & 3);
            w0[cc] = (__bf16)tile[nl0][dd];
            w1[cc] = (__bf16)tile[nl1][dd];
        }
        *(bf16x8*)dstrow = w0;
        *(bf16x8*)(dstrow + 8) = w1;
    } else {
        __bf16* dst = (part == 0) ? qb : kb;
        const float sc = (part == 0) ? QSCALE : 1.0f;
        int mbase = w * 16 + lh * 4;
#pragma unroll
        for (int fj = 0; fj < 4; ++fj) {
            int dd = fj * 16 + lr;
            float bias = bqkv[head * 192 + part * 64 + dd];
#pragma unroll
            for (int r = 0; r < 4; ++r) {
                int n = n0 + mbase + r;
                dst[((size_t)((b * 4 + head) * 4096 + n)) * 64 + dd] = (__bf16)((acc[fj][r] + bias) * sc);
            }
        }
    }
}

// ---------------------------------------------------------------------------
// 4) Flash attention, swapped-operand, STATIC softmax, 32x32x16 MFMAs,
//    V^T-in-global (kappa-ordered), FRAGMENT-MAJOR LDS:
//      chunk c = ks*128 + b32*64 + lane at byte c*16 holds exactly the 16B
//      lane needs for fragment (ks, b32) -> reads are base + l*16 with
//      immediate offsets (conflict-free; same pattern staging writes).
//    Grid 512 (XCD swizzle), 4 waves x 32 q-rows (128-row supertile).
// ---------------------------------------------------------------------------
__global__ __launch_bounds__(256, 2) void attn_fwd(const __bf16* __restrict__ q,
                                                   const __bf16* __restrict__ k,
                                                   const __bf16* __restrict__ vt,
                                                   __bf16* __restrict__ ao) {
    const int id = blockIdx.x;
    const int within = id >> 3;                       // 0..63
    const int bh = ((id & 7) << 1) + (within >> 5);   // XCD (id&7) owns bh pair
    const int q0 = (within & 31) * 128;
    const int tid = threadIdx.x;
    const int wv = tid >> 6, l = tid & 63;
    const int l31 = l & 31, h = l >> 5;

    __shared__ __attribute__((aligned(16))) char smem[32768];  // K dbuf 16K | V^T dbuf 16K

    const size_t base = (size_t)bh * (4096 * 64);

    // ---- staging source offsets (chunk c = wv*64 + l, and +256) ----
    // frag decomposition: ks = c>>7, b32 = (c>>6)&1, lane = c&63
    auto ksrc = [](int c) -> int {
        int ks = c >> 7, b32 = (c >> 6) & 1, ll = c & 63;
        return ((ll & 31) + 32 * b32) * 64 + ks * 16 + (ll >> 5) * 8;
    };
    auto vsrc = [](int c) -> int {
        int ks = c >> 7, b32 = (c >> 6) & 1, ll = c & 63;
        return ((ll & 31) + 32 * b32) * 4096 + ks * 16 + (ll >> 5) * 8;
    };
    const int c0 = wv * 64 + l;
    const int gk0 = ksrc(c0), gk1 = ksrc(c0 + 256);
    const int gv0 = vsrc(c0), gv1 = vsrc(c0 + 256);
    const int lw0 = wv * 1024;                                  // wave-uniform LDS bases
    const int lw1 = 4096 + wv * 1024;

    const __bf16* kg = k + base;
    const __bf16* vg = vt + base;   // V^T [64][4096]

    // Q B-frags: lane holds Q[q = q0+wv*32+l31][ks*16 + h*8 + e]
    bf16x8 qf[4];
    {
        const __bf16* qp = q + base + (size_t)(q0 + wv * 32 + l31) * 64 + h * 8;
#pragma unroll
        for (int ks = 0; ks < 4; ++ks) qf[ks] = *(const bf16x8*)(qp + ks * 16);
    }
    bf16x8 ones;
#pragma unroll
    for (int e = 0; e < 8; ++e) ones[e] = (__bf16)1.0f;

    f32x16 O0 = (f32x16)0.0f, O1 = (f32x16)0.0f, LS = (f32x16)0.0f;

    // prologue: stage tile 0 into buf 0
    gload16(kg + gk0, smem + lw0);
    gload16(kg + gk1, smem + lw1);
    gload16(vg + gv0, smem + 16384 + lw0);
    gload16(vg + gv1, smem + 16384 + lw1);
    __syncthreads();

    const unsigned lb = (unsigned)(l * 16);   // per-lane fragment byte offset

    auto body = [&](const char* Kc, const char* Vc, char* kd, char* vd, int tnext) {
        // issue next-tile staging into the other buffer
        if (tnext < 64) {
            const __bf16* kp = kg + (size_t)tnext * 4096;
            const __bf16* vp = vg + (size_t)tnext * 64;
            gload16(kp + gk0, kd + lw0);
            gload16(kp + gk1, kd + lw1);
            gload16(vp + gv0, vd + lw0);
            gload16(vp + gv1, vd + lw1);
        }
        const char* Kl = Kc + lb;
        const char* Vl = Vc + lb;

        // ---- S^T = K Q^T (2 x 4 chained MFMA32) ----
        f32x16 S0 = (f32x16)0.0f, S1 = (f32x16)0.0f;
        __builtin_amdgcn_s_setprio(1);
#pragma unroll
        for (int ks = 0; ks < 4; ++ks) {
            bf16x8 ka0 = *(const bf16x8*)(Kl + ks * 2048);
            bf16x8 ka1 = *(const bf16x8*)(Kl + ks * 2048 + 1024);
            S0 = MFMA32(ka0, qf[ks], S0);
            S1 = MFMA32(ka1, qf[ks], S1);
        }
        __builtin_amdgcn_s_setprio(0);

        // ---- static softmax: B_s[e] = bf16(exp2(S regs)) — identity map ----
        bf16x8 B0, B1, B2, B3;
#pragma unroll
        for (int e = 0; e < 8; ++e) {
            B0[e] = (__bf16)__builtin_amdgcn_exp2f(S0[e]);
            B1[e] = (__bf16)__builtin_amdgcn_exp2f(S0[8 + e]);
            B2[e] = (__bf16)__builtin_amdgcn_exp2f(S1[e]);
            B3[e] = (__bf16)__builtin_amdgcn_exp2f(S1[8 + e]);
        }

        // ---- O^T += V^T P ; lsum via ones-MFMA (A-frags: conflict-free b128) ----
        __builtin_amdgcn_s_setprio(1);
        {
            bf16x8 v00 = *(const bf16x8*)(Vl + 0 * 2048);
            bf16x8 v10 = *(const bf16x8*)(Vl + 0 * 2048 + 1024);
            O0 = MFMA32(v00, B0, O0);
            O1 = MFMA32(v10, B0, O1);
            LS = MFMA32(ones, B0, LS);
            bf16x8 v01 = *(const bf16x8*)(Vl + 1 * 2048);
            bf16x8 v11 = *(const bf16x8*)(Vl + 1 * 2048 + 1024);
            O0 = MFMA32(v01, B1, O0);
            O1 = MFMA32(v11, B1, O1);
            LS = MFMA32(ones, B1, LS);
            bf16x8 v02 = *(const bf16x8*)(Vl + 2 * 2048);
            bf16x8 v12 = *(const bf16x8*)(Vl + 2 * 2048 + 1024);
            O0 = MFMA32(v02, B2, O0);
            O1 = MFMA32(v12, B2, O1);
            LS = MFMA32(ones, B2, LS);
            bf16x8 v03 = *(const bf16x8*)(Vl + 3 * 2048);
            bf16x8 v13 = *(const bf16x8*)(Vl + 3 * 2048 + 1024);
            O0 = MFMA32(v03, B3, O0);
            O1 = MFMA32(v13, B3, O1);
            LS = MFMA32(ones, B3, LS);
        }
        __builtin_amdgcn_s_setprio(0);

        __syncthreads();   // implicit vmcnt(0): staging landed; buf flip safe
    };

    for (int t = 0; t < 64; t += 2) {
        body(smem,        smem + 16384,        smem + 8192, smem + 16384 + 8192, t + 1);
        body(smem + 8192, smem + 16384 + 8192, smem,        smem + 16384,        t + 2);
    }

    // epilogue: every lane holds the full denominator in LS (any reg)
    float inv = 1.0f / LS[0];
    int b = bh >> 2, hd = bh & 3;
    int n = q0 + wv * 32 + l31;
    __bf16* dst = ao + ((size_t)(b * 4096 + n)) * 256 + hd * 64 + h * 4;
#pragma unroll
    for (int dt = 0; dt < 2; ++dt) {
        const f32x16& O = dt ? O1 : O0;
#pragma unroll
        for (int g = 0; g < 4; ++g) {
            bf16x4 pk;
#pragma unroll
            for (int m = 0; m < 4; ++m) pk[m] = (__bf16)(O[g * 4 + m] * inv);
            *(bf16x4*)(dst + dt * 32 + g * 8) = pk;
        }
    }
}

// ---------------------------------------------------------------------------
// 5) out projection + bias + residual + 1/sqrt(2), transposed store [B,C,N]
// ---------------------------------------------------------------------------
__global__ __launch_bounds__(256) void out_gemm(const __bf16* __restrict__ ao,
                                                const __bf16* __restrict__ wf,
                                                const float* __restrict__ bout,
                                                const float* __restrict__ x,
                                                float* __restrict__ out) {
    const int mt = blockIdx.x, nt = blockIdx.y;
    const int tid = threadIdx.x;
    const int w = tid >> 6, l = tid & 63;
    const int lr = l & 15, lh = l >> 4;
    f32x4 acc[4] = {{0.f,0.f,0.f,0.f},{0.f,0.f,0.f,0.f},{0.f,0.f,0.f,0.f},{0.f,0.f,0.f,0.f}};
    const __bf16* ap = ao + (size_t)(mt * 64 + w * 16 + lr) * 256 + lh * 8;
#pragma unroll
    for (int kk = 0; kk < 8; ++kk) {
        bf16x8 a = *(const bf16x8*)(ap + kk * 32);
#pragma unroll
        for (int fj = 0; fj < 4; ++fj) {
            bf16x8 bf = *(const bf16x8*)(wf + (size_t)(((nt * 4 + fj) * 8 + kk) * 64 + l) * 8);
            acc[fj] = MFMA16(a, bf, acc[fj]);
        }
    }
    __shared__ float tile[64][72];
#pragma unroll
    for (int fj = 0; fj < 4; ++fj) {
        float bias = bout[nt * 64 + fj * 16 + lr];
#pragma unroll
        for (int r = 0; r < 4; ++r)
            tile[w * 16 + lh * 4 + r][fj * 16 + lr] = acc[fj][r] + bias;
    }
    __syncthreads();
    int b  = mt >> 6;
    int n0 = (mt & 63) * 64;
    int c0 = nt * 64;
    int cl = tid >> 2, nq = tid & 3;
    size_t gbase = ((size_t)(b * 256 + c0 + cl)) * 4096 + n0 + nq * 16;
#pragma unroll
    for (int i = 0; i < 16; i += 4) {
        float4 xv = *(const float4*)(x + gbase + i);
        float4 ov;
        ov.x = (tile[nq * 16 + i + 0][cl] + xv.x) * 0.70710678118654752f;
        ov.y = (tile[nq * 16 + i + 1][cl] + xv.y) * 0.70710678118654752f;
        ov.z = (tile[nq * 16 + i + 2][cl] + xv.z) * 0.70710678118654752f;
        ov.w = (tile[nq * 16 + i + 3][cl] + xv.w) * 0.70710678118654752f;
        *(float4*)(out + gbase + i) = ov;
    }
}

// ---------------------------------------------------------------------------
extern "C" void kernel_launch(void* const* d_in, const int* in_sizes, int n_in,
                              void* d_out, int out_size, void* d_ws, size_t ws_size,
                              hipStream_t stream) {
    const float* x     = (const float*)d_in[0];
    const float* gamma = (const float*)d_in[1];
    const float* beta  = (const float*)d_in[2];
    const float* W_qkv = (const float*)d_in[3];
    const float* b_qkv = (const float*)d_in[4];
    const float* W_out = (const float*)d_in[5];
    const float* b_out = (const float*)d_in[6];
    float* out = (float*)d_out;
    char* ws = (char*)d_ws;

    __bf16* wqf   = (__bf16*)(ws + OFF_WQKV);
    __bf16* wof   = (__bf16*)(ws + OFF_WOUT);
    float2* stats = (float2*)(ws + OFF_STATS);
    __bf16* hid   = (__bf16*)(ws + OFF_HID);   // hid, then attn_out
    __bf16* qb    = (__bf16*)(ws + OFF_Q);
    __bf16* kb    = (__bf16*)(ws + OFF_K);
    __bf16* vbt   = (__bf16*)(ws + OFF_V);     // V^T kappa-ordered

    pre_kernel<<<1152, 256, 0, stream>>>(x, stats, W_qkv, W_out, wqf, wof);
    gn_apply<<<256, 256, 0, stream>>>(x, gamma, beta, stats, hid);
    qkv_gemm<<<dim3(256, 12), 256, 0, stream>>>(hid, wqf, b_qkv, qb, kb, vbt);
    attn_fwd<<<512, 256, 0, stream>>>(qb, kb, vbt, hid);
    out_gemm<<<dim3(256, 4), 256, 0, stream>>>(hid, wof, b_out, x, out);
}